// Round 1
// baseline (28373.474 us; speedup 1.0000x reference)
//
#include <hip/hip_runtime.h>

// Problem constants (fixed by setup_inputs):
//   imgs (2,16,3,224,224) [only shapes used], i_features (8,256,56,56),
//   p_motions (2,12,2,112,112) -> N=24 frames, C=256, H=W=56, k=3 repeat.
#define NPIX 3136   // 56*56
#define NN   24     // B*Tp
#define CDIM 256

// ---------------- resize(112->56) * scale(0.25) == avg2x2 * 0.0625 ----------
__global__ __launch_bounds__(256) void resize_pm_kernel(
    const float* __restrict__ pmo, float* __restrict__ pm)
{
    int idx = blockIdx.x * 256 + threadIdx.x;
    if (idx >= NN * 2 * NPIX) return;
    int x = idx % 56;
    int y = (idx / 56) % 56;
    int nc = idx / NPIX;  // n*2 + c
    const float* src = pmo + (size_t)nc * 112 * 112 + (size_t)(2 * y) * 112 + 2 * x;
    pm[idx] = (src[0] + src[1] + src[112] + src[113]) * 0.0625f;
}

// ---------------- direct conv KSxKS, SAME padding, H=W=56 -------------------
// Block: 256 threads = 4 cout-groups(8 couts) x 64 pixel-blocks(2x2 px).
// Tile: 32 couts x 16x16 pixels. Cin chunked by 8 through LDS.
template <int KS, bool RELU>
__global__ __launch_bounds__(256) void conv_kernel(
    const float* __restrict__ in, const float* __restrict__ wgt,
    const float* __restrict__ bias, float* __restrict__ out,
    int Cin, int Cout)
{
    constexpr int CK = 8;
    constexpr int HALO = KS / 2;
    constexpr int TH = 16, TW = 16;
    constexpr int ITH = TH + 2 * HALO;
    constexpr int ITW = TW + 2 * HALO;
    constexpr int ITWP = ITW + 1;  // +1 pad to break power-of-2 bank strides
    constexpr int KK = KS * KS;

    __shared__ float sIn[CK][ITH][ITWP];
    __shared__ float sW[32][CK][KK];

    const int tid = threadIdx.x;
    const int tile = blockIdx.x;       // 0..15 (4x4 tiles of 16x16 covering 56x56, ragged)
    const int coutBase = blockIdx.y * 32;
    const int n = blockIdx.z;
    const int y0t = (tile >> 2) * TH;
    const int x0t = (tile & 3) * TW;

    const int pb = tid & 63;           // pixel-block id (wave-local)
    const int cg = tid >> 6;           // cout group == wave id (wave-uniform)
    const int ly = (pb >> 3) * 2;      // 0..14
    const int lx = (pb & 7) * 2;       // 0..14

    float acc[8][4];
#pragma unroll
    for (int j = 0; j < 8; j++)
#pragma unroll
        for (int q = 0; q < 4; q++) acc[j][q] = 0.f;

    const float* inN = in + (size_t)n * Cin * NPIX;

    for (int c0 = 0; c0 < Cin; c0 += CK) {
        // stage input tile (zero-padded: halo, image edge, cin tail)
        for (int idx = tid; idx < CK * ITH * ITW; idx += 256) {
            int ci = idx / (ITH * ITW);
            int rem = idx - ci * (ITH * ITW);
            int iy = rem / ITW, ix = rem - iy * ITW;
            int gy = y0t + iy - HALO, gx = x0t + ix - HALO;
            int cc = c0 + ci;
            float v = 0.f;
            if (cc < Cin && (unsigned)gy < 56u && (unsigned)gx < 56u)
                v = inN[((size_t)cc * 56 + gy) * 56 + gx];
            sIn[ci][iy][ix] = v;
        }
        // stage weights (Cout,Cin,KS,KS)
        for (int idx = tid; idx < 32 * CK * KK; idx += 256) {
            int co = idx / (CK * KK);
            int rem = idx - co * (CK * KK);
            int ci = rem / KK, k = rem - ci * KK;
            int cc = c0 + ci;
            float v = 0.f;
            if (cc < Cin)
                v = wgt[((size_t)(coutBase + co) * Cin + cc) * KK + k];
            sW[co][ci][k] = v;
        }
        __syncthreads();

#pragma unroll
        for (int ci = 0; ci < CK; ci++) {
            float r[KS + 1][KS + 1];
#pragma unroll
            for (int ny = 0; ny < KS + 1; ny++)
#pragma unroll
                for (int nx = 0; nx < KS + 1; nx++)
                    r[ny][nx] = sIn[ci][ly + ny][lx + nx];
#pragma unroll
            for (int j = 0; j < 8; j++) {
                float w[KK];
#pragma unroll
                for (int k = 0; k < KK; k++) w[k] = sW[cg * 8 + j][ci][k];  // wave-uniform -> LDS broadcast
#pragma unroll
                for (int py = 0; py < 2; py++)
#pragma unroll
                    for (int px = 0; px < 2; px++) {
                        float s = 0.f;
#pragma unroll
                        for (int ky = 0; ky < KS; ky++)
#pragma unroll
                            for (int kx = 0; kx < KS; kx++)
                                s += r[py + ky][px + kx] * w[ky * KS + kx];
                        acc[j][py * 2 + px] += s;
                    }
            }
        }
        __syncthreads();
    }

    // epilogue: bias (+relu), masked store (ragged 56 vs 64)
#pragma unroll
    for (int j = 0; j < 8; j++) {
        int co = coutBase + cg * 8 + j;
        float b = bias[co];
#pragma unroll
        for (int py = 0; py < 2; py++) {
            int y = y0t + ly + py;
            if (y >= 56) continue;
#pragma unroll
            for (int px = 0; px < 2; px++) {
                int x = x0t + lx + px;
                if (x >= 56) continue;
                float v = acc[j][py * 2 + px] + b;
                if (RELU) v = fmaxf(v, 0.f);
                out[((size_t)n * Cout + co) * NPIX + (size_t)y * 56 + x] = v;
            }
        }
    }
}

// ---------------- deformable 1x1 bilinear sampling --------------------------
__global__ __launch_bounds__(256) void deform_kernel(
    const float* __restrict__ feat,  // i_features (8,256,56,56)
    const float* __restrict__ pm,    // (24,2,56,56) resized+scaled offsets
    float* __restrict__ out)         // (24,256,56,56)
{
    int idx = blockIdx.x * 256 + threadIdx.x;
    if (idx >= NN * CDIM * NPIX) return;
    int x = idx % 56;
    int y = (idx / 56) % 56;
    int c = (idx / NPIX) % CDIM;
    int n = idx / (NPIX * CDIM);
    int fi = n / 3;  // repeat(i_features, k=3)
    const float* f = feat + ((size_t)fi * CDIM + c) * NPIX;
    float dy = pm[((size_t)n * 2 + 0) * NPIX + y * 56 + x];
    float dx = pm[((size_t)n * 2 + 1) * NPIX + y * 56 + x];
    float gy = (float)y + dy, gx = (float)x + dx;
    float y0f = floorf(gy), x0f = floorf(gx);
    float ty = gy - y0f, tx = gx - x0f;
    int y0 = (int)y0f, x0 = (int)x0f;
    int y1 = y0 + 1, x1 = x0 + 1;
    float v00 = ((unsigned)y0 < 56u && (unsigned)x0 < 56u) ? f[y0 * 56 + x0] : 0.f;
    float v01 = ((unsigned)y0 < 56u && (unsigned)x1 < 56u) ? f[y0 * 56 + x1] : 0.f;
    float v10 = ((unsigned)y1 < 56u && (unsigned)x0 < 56u) ? f[y1 * 56 + x0] : 0.f;
    float v11 = ((unsigned)y1 < 56u && (unsigned)x1 < 56u) ? f[y1 * 56 + x1] : 0.f;
    out[idx] = v00 * (1.f - ty) * (1.f - tx) + v01 * (1.f - ty) * tx +
               v10 * ty * (1.f - tx) + v11 * ty * tx;
}

// ---------------- p2d = pf + emb (in d_out), pooled = mean_hw ---------------
__global__ __launch_bounds__(256) void final_kernel(
    const float* __restrict__ pf, float* __restrict__ dout)
{
    int b = blockIdx.x;  // 0..6143 == n*256 + c  (matches pooled flat layout)
    const float* p = pf + (size_t)b * NPIX;
    float* p2d = dout + 6144 + (size_t)b * NPIX;
    int tid = threadIdx.x;
    float s = 0.f;
    for (int i = tid; i < NPIX; i += 256) {
        float v = p[i] + p2d[i];  // p2d region currently holds emb
        p2d[i] = v;
        s += v;
    }
#pragma unroll
    for (int off = 32; off > 0; off >>= 1) s += __shfl_down(s, off, 64);
    __shared__ float ps[4];
    if ((tid & 63) == 0) ps[tid >> 6] = s;
    __syncthreads();
    if (tid == 0) dout[b] = (ps[0] + ps[1] + ps[2] + ps[3]) * (1.f / 3136.f);
}

extern "C" void kernel_launch(void* const* d_in, const int* in_sizes, int n_in,
                              void* d_out, int out_size, void* d_ws, size_t ws_size,
                              hipStream_t stream)
{
    const float* i_features = (const float*)d_in[1];
    const float* p_motions  = (const float*)d_in[2];
    const float* dw  = (const float*)d_in[3];
    const float* db  = (const float*)d_in[4];
    const float* mw1 = (const float*)d_in[5];
    const float* mb1 = (const float*)d_in[6];
    const float* mw2 = (const float*)d_in[7];
    const float* mb2 = (const float*)d_in[8];
    const float* mw3 = (const float*)d_in[9];
    const float* mb3 = (const float*)d_in[10];
    const float* ew1 = (const float*)d_in[11];
    const float* eb1 = (const float*)d_in[12];
    const float* ew2 = (const float*)d_in[13];
    const float* eb2 = (const float*)d_in[14];
    const float* ew3 = (const float*)d_in[15];
    const float* eb3 = (const float*)d_in[16];
    const float* ew4 = (const float*)d_in[17];
    const float* eb4 = (const float*)d_in[18];
    float* out = (float*)d_out;

    // workspace layout: pm (150528) | bufA (19267584) | bufB (19267584) floats
    float* pm   = (float*)d_ws;
    float* bufA = pm + 150528;
    float* bufB = bufA + (size_t)NN * CDIM * NPIX;
    float* emb  = out + 6144;  // emb lives in d_out's p2d region until final add

    resize_pm_kernel<<<(NN * 2 * NPIX + 255) / 256, 256, 0, stream>>>(p_motions, pm);

    dim3 cgrid(16, 8, NN);  // 16 spatial tiles x (256/32) cout tiles x 24 imgs
    // emb chain
    conv_kernel<3, true><<<cgrid, 256, 0, stream>>>(pm,   ew1, eb1, bufA, 2,   256);
    conv_kernel<3, true><<<cgrid, 256, 0, stream>>>(bufA, ew2, eb2, bufB, 256, 256);
    conv_kernel<3, true><<<cgrid, 256, 0, stream>>>(bufB, ew3, eb3, bufA, 256, 256);
    conv_kernel<3, true><<<cgrid, 256, 0, stream>>>(bufA, ew4, eb4, emb,  256, 256);
    // deform sample + 1x1 projection
    deform_kernel<<<(NN * CDIM * NPIX + 255) / 256, 256, 0, stream>>>(i_features, pm, bufA);
    conv_kernel<1, false><<<cgrid, 256, 0, stream>>>(bufA, dw, db, bufB, 256, 256);
    // pf chain
    conv_kernel<3, true><<<cgrid, 256, 0, stream>>>(bufB, mw1, mb1, bufA, 256, 256);
    conv_kernel<3, true><<<cgrid, 256, 0, stream>>>(bufA, mw2, mb2, bufB, 256, 256);
    conv_kernel<3, true><<<cgrid, 256, 0, stream>>>(bufB, mw3, mb3, bufA, 256, 256);
    // p2d = pf + emb, pooled = mean
    final_kernel<<<NN * CDIM, 256, 0, stream>>>(bufA, out);
}

// Round 2
// 1200.500 us; speedup vs baseline: 23.6347x; 23.6347x over previous
//
#include <hip/hip_runtime.h>

// Shapes: imgs(2,16,3,224,224)[shape only], i_features(8,256,56,56) fp32,
// p_motions(2,12,2,112,112) fp32 -> N=24 frames, C=256, H=W=56, k=3.
#define NPIX 3136
#define NN   24
#define CDIM 256

typedef __attribute__((ext_vector_type(8))) short short8v;   // 8 bf16 (A/B frag)
typedef __attribute__((ext_vector_type(4))) float float4v;   // 4 fp32 (C/D frag)

static __device__ __forceinline__ unsigned short f2b(float f) {
    unsigned int u = __float_as_uint(f);
    u = (u + 0x7FFFu + ((u >> 16) & 1u)) >> 16;   // RNE
    return (unsigned short)u;
}
static __device__ __forceinline__ float b2f(unsigned short h) {
    return __uint_as_float(((unsigned int)h) << 16);
}

// ---------------- resize(112->56)*scale == avg2x2 * 0.0625 ------------------
__global__ __launch_bounds__(256) void resize_pm_kernel(
    const float* __restrict__ pmo, float* __restrict__ pm)
{
    int idx = blockIdx.x * 256 + threadIdx.x;
    if (idx >= NN * 2 * NPIX) return;
    int x = idx % 56, y = (idx / 56) % 56, nc = idx / NPIX;
    const float* src = pmo + (size_t)nc * 112 * 112 + (size_t)(2 * y) * 112 + 2 * x;
    pm[idx] = (src[0] + src[1] + src[112] + src[113]) * 0.0625f;
}

// ---------------- weight packing -------------------------------------------
// 3x3: src fp32 (co,ci,3,3) -> dst bf16 [chunk8][co256][tap*32+ci32]
__global__ __launch_bounds__(256) void pack3_kernel(
    const float* __restrict__ w, unsigned short* __restrict__ dst)
{
    int d = blockIdx.x * 256 + threadIdx.x;
    if (d >= 8 * 256 * 288) return;
    int ch = d / (256 * 288);
    int r  = d % (256 * 288);
    int co = r / 288, kk = r % 288;
    int tap = kk >> 5, cw = kk & 31;
    dst[d] = f2b(w[(size_t)co * 2304 + (size_t)(ch * 32 + cw) * 9 + tap]);
}
// 1x1: src fp32 dw(o,c) -> dst bf16 [chunk8][co256][ci32]
__global__ __launch_bounds__(256) void pack1_kernel(
    const float* __restrict__ w, unsigned short* __restrict__ dst)
{
    int d = blockIdx.x * 256 + threadIdx.x;
    if (d >= 8 * 256 * 32) return;
    int ch = d / (256 * 32);
    int co = (d / 32) % 256, cw = d & 31;
    dst[d] = f2b(w[(size_t)co * 256 + ch * 32 + cw]);
}

// ---------------- ew1 conv (Cin=2, K=18) fp32 direct -> bf16 NHWC + relu ----
__global__ __launch_bounds__(256) void ew1_kernel(
    const float* __restrict__ pm, const float* __restrict__ w,   // (256,2,3,3)
    const float* __restrict__ b, unsigned short* __restrict__ out)
{
    __shared__ float sT[8][18];
    __shared__ float sW1[256 * 19];
    int n = blockIdx.y;
    int pixbase = blockIdx.x * 8;
    int t = threadIdx.x;
    if (t < 144) {
        int p = t / 18, j = t % 18;
        int ci = j / 9, tap = j % 9;
        int pix = pixbase + p;
        int y = pix / 56, x = pix % 56;
        int yy = y + tap / 3 - 1, xx = x + tap % 3 - 1;
        float v = 0.f;
        if ((unsigned)yy < 56u && (unsigned)xx < 56u)
            v = pm[((size_t)n * 2 + ci) * NPIX + yy * 56 + xx];
        sT[p][j] = v;
    }
    for (int idx = t; idx < 4608; idx += 256) {
        int co = idx / 18, j = idx % 18;
        sW1[co * 19 + j] = w[idx];
    }
    __syncthreads();
    int co = t;
    float bias = b[co];
#pragma unroll
    for (int p = 0; p < 8; p++) {
        float acc = bias;
#pragma unroll
        for (int j = 0; j < 18; j++) acc += sT[p][j] * sW1[co * 19 + j];
        acc = fmaxf(acc, 0.f);
        out[((size_t)n * NPIX + pixbase + p) * 256 + co] = f2b(acc);
    }
}

// ---------------- MFMA implicit-GEMM conv (NHWC bf16 -> NHWC bf16) ----------
// Tile: 64 cout x 256 px (16x16 spatial); 4 waves each 64co x 64px.
// K ordered: ci-chunk(32) outer, tap inner. Weights pre-packed.
template <int TAPS, bool RELU, bool HASB>
__global__ __launch_bounds__(256, 2) void conv_mfma(
    const unsigned short* __restrict__ in,   // (NI,3136,256) bf16
    const unsigned short* __restrict__ wp,   // [8][256][TAPS*32]
    const float* __restrict__ bias,
    unsigned short* __restrict__ out)
{
    constexpr int HALO = (TAPS == 9) ? 1 : 0;
    constexpr int IT   = 16 + 2 * HALO;           // 18 or 16
    constexpr int KKC  = TAPS * 32;               // 288 or 32
    constexpr int KP   = (TAPS == 9) ? 296 : 56;  // padded LDS stride (bank-checked)
    __shared__ unsigned short sIn[IT * IT * 32];
    __shared__ unsigned short sW[64 * KP];

    const int tid  = threadIdx.x;
    const int lane = tid & 63;
    const int wv   = tid >> 6;
    const int col  = lane & 15;
    const int quad = lane >> 4;
    const int tile = blockIdx.x;
    const int coBase = blockIdx.y * 64;
    const int n = blockIdx.z;
    const int ty0 = (tile >> 2) * 16;
    const int tx0 = (tile & 3) * 16;

    const unsigned short* inN = in + (size_t)n * NPIX * 256;

    float4v acc[4][4];
#pragma unroll
    for (int mi = 0; mi < 4; mi++)
#pragma unroll
        for (int nj = 0; nj < 4; nj++) acc[mi][nj] = (float4v){0.f, 0.f, 0.f, 0.f};

    for (int ch = 0; ch < 8; ch++) {
        const int c0 = ch * 32;
        // stage input halo tile [pix][32ci], b128 per thread
        for (int i = tid; i < IT * IT * 4; i += 256) {
            int ci8 = i & 3, pix = i >> 2;
            int iy = pix / IT, ix = pix % IT;
            int gy = ty0 + iy - HALO, gx = tx0 + ix - HALO;
            int4 v = {0, 0, 0, 0};
            if ((unsigned)gy < 56u && (unsigned)gx < 56u)
                v = *(const int4*)(inN + ((size_t)(gy * 56 + gx) * 256 + c0 + ci8 * 8));
            *(int4*)(sIn + pix * 32 + ci8 * 8) = v;
        }
        // stage weights [co64][KKC] -> padded KP
        const unsigned short* wsrc = wp + ((size_t)ch * 256 + coBase) * KKC;
        for (int i = tid; i < 64 * (KKC / 8); i += 256) {
            int co = i / (KKC / 8), j = i % (KKC / 8);
            *(int4*)(sW + co * KP + j * 8) = *(const int4*)(wsrc + co * KKC + j * 8);
        }
        __syncthreads();
#pragma unroll
        for (int tap = 0; tap < TAPS; tap++) {
            const int dy = (TAPS == 9) ? tap / 3 : 0;
            const int dx = (TAPS == 9) ? tap % 3 : 0;
            short8v a[4], b[4];
#pragma unroll
            for (int nj = 0; nj < 4; nj++) {
                int r = wv * 4 + nj;
                b[nj] = *(const short8v*)(sIn + ((r + dy) * IT + col + dx) * 32 + quad * 8);
            }
#pragma unroll
            for (int mi = 0; mi < 4; mi++)
                a[mi] = *(const short8v*)(sW + (mi * 16 + col) * KP + tap * 32 + quad * 8);
#pragma unroll
            for (int mi = 0; mi < 4; mi++)
#pragma unroll
                for (int nj = 0; nj < 4; nj++)
                    acc[mi][nj] = __builtin_amdgcn_mfma_f32_16x16x32_bf16(
                        a[mi], b[nj], acc[mi][nj], 0, 0, 0);
        }
        __syncthreads();
    }
    // epilogue: D row = quad*4+reg (cout), col = pixel
    const int x = tx0 + col;
#pragma unroll
    for (int mi = 0; mi < 4; mi++) {
        float4v bv = (float4v){0.f, 0.f, 0.f, 0.f};
        if (HASB) bv = *(const float4v*)(bias + coBase + mi * 16 + quad * 4);
#pragma unroll
        for (int nj = 0; nj < 4; nj++) {
            int y = ty0 + wv * 4 + nj;
            if (y < 56 && x < 56) {
                float v0 = acc[mi][nj][0] + bv[0];
                float v1 = acc[mi][nj][1] + bv[1];
                float v2 = acc[mi][nj][2] + bv[2];
                float v3 = acc[mi][nj][3] + bv[3];
                if (RELU) {
                    v0 = fmaxf(v0, 0.f); v1 = fmaxf(v1, 0.f);
                    v2 = fmaxf(v2, 0.f); v3 = fmaxf(v3, 0.f);
                }
                uint2 pk;
                pk.x = (unsigned)f2b(v0) | ((unsigned)f2b(v1) << 16);
                pk.y = (unsigned)f2b(v2) | ((unsigned)f2b(v3) << 16);
                *(uint2*)(out + ((size_t)n * NPIX + y * 56 + x) * 256 +
                          coBase + mi * 16 + quad * 4) = pk;
            }
        }
    }
}

// ---------------- i_features NCHW fp32 -> NHWC bf16 -------------------------
__global__ __launch_bounds__(256) void transpose_fI(
    const float* __restrict__ feat, unsigned short* __restrict__ dst)
{
    __shared__ float s[64][65];
    int fi = blockIdx.z;
    int p0 = blockIdx.x * 64;
    int c0 = blockIdx.y * 64;
    int t = threadIdx.x;
    int pl = t & 63, cq = t >> 6;
#pragma unroll
    for (int i = 0; i < 16; i++) {
        int c = cq + i * 4;
        s[pl][c] = feat[((size_t)fi * 256 + c0 + c) * NPIX + p0 + pl];
    }
    __syncthreads();
    int cl = t & 63, pq = t >> 6;
#pragma unroll
    for (int i = 0; i < 16; i++) {
        int p = pq + i * 4;
        dst[((size_t)fi * NPIX + p0 + p) * 256 + c0 + cl] = f2b(s[p][cl]);
    }
}

// ---------------- deform sampling of Z (NHWC bf16) + db ---------------------
__global__ __launch_bounds__(256) void deform_kernel(
    const unsigned short* __restrict__ Z,   // (8,3136,256) bf16
    const float* __restrict__ pm,           // (24,2,3136) fp32
    const float* __restrict__ db,
    unsigned short* __restrict__ out)       // (24,3136,256) bf16
{
    int n = blockIdx.y;
    int t = threadIdx.x;
    int pix = blockIdx.x * 8 + (t >> 5);
    int g = t & 31;                  // 8-channel group
    int fi = n / 3;
    int y = pix / 56, x = pix % 56;
    float dy = pm[((size_t)n * 2 + 0) * NPIX + pix];
    float dx = pm[((size_t)n * 2 + 1) * NPIX + pix];
    float gy = (float)y + dy, gx = (float)x + dx;
    float y0f = floorf(gy), x0f = floorf(gx);
    float ty = gy - y0f, tx = gx - x0f;
    int y0 = (int)y0f, x0 = (int)x0f, y1 = y0 + 1, x1 = x0 + 1;
    bool vy0 = (unsigned)y0 < 56u, vy1 = (unsigned)y1 < 56u;
    bool vx0 = (unsigned)x0 < 56u, vx1 = (unsigned)x1 < 56u;
    float w00 = (1.f - ty) * (1.f - tx) * (vy0 && vx0 ? 1.f : 0.f);
    float w01 = (1.f - ty) * tx * (vy0 && vx1 ? 1.f : 0.f);
    float w10 = ty * (1.f - tx) * (vy1 && vx0 ? 1.f : 0.f);
    float w11 = ty * tx * (vy1 && vx1 ? 1.f : 0.f);
    int y0c = vy0 ? y0 : 0, y1c = vy1 ? y1 : 0;
    int x0c = vx0 ? x0 : 0, x1c = vx1 ? x1 : 0;
    const unsigned short* Zf = Z + (size_t)fi * NPIX * 256 + g * 8;
    const unsigned short* p00 = Zf + (size_t)(y0c * 56 + x0c) * 256;
    const unsigned short* p01 = Zf + (size_t)(y0c * 56 + x1c) * 256;
    const unsigned short* p10 = Zf + (size_t)(y1c * 56 + x0c) * 256;
    const unsigned short* p11 = Zf + (size_t)(y1c * 56 + x1c) * 256;
    unsigned short r[8];
#pragma unroll
    for (int j = 0; j < 8; j++) {
        float v = b2f(p00[j]) * w00 + b2f(p01[j]) * w01 +
                  b2f(p10[j]) * w10 + b2f(p11[j]) * w11;
        v += db[g * 8 + j];
        r[j] = f2b(v);
    }
    *(int4*)(out + ((size_t)n * NPIX + pix) * 256 + g * 8) = *(int4*)r;
}

// ---------------- final: p2d = pf+emb -> fp32 NCHW, pooled partial ----------
__global__ __launch_bounds__(256) void final_kernel(
    const unsigned short* __restrict__ pf, const unsigned short* __restrict__ emb,
    float* __restrict__ dout, float* __restrict__ acc)
{
    __shared__ float s[64 * 135];
    int n = blockIdx.y;
    int p0 = blockIdx.x * 64;
    int t = threadIdx.x;
    float* p2d = dout + 6144 + (size_t)n * CDIM * NPIX;
    for (int cpass = 0; cpass < 2; cpass++) {
        int cb = cpass * 128;
        // phase1: coalesced NHWC reads -> LDS [p][c]
        int g = t & 15, pq = t >> 4;
#pragma unroll
        for (int ii = 0; ii < 4; ii++) {
            int p = pq + ii * 16;
            size_t base = ((size_t)n * NPIX + p0 + p) * 256 + cb + g * 8;
            int4 a4 = *(const int4*)(pf + base);
            int4 b4 = *(const int4*)(emb + base);
            const unsigned short* au = (const unsigned short*)&a4;
            const unsigned short* bu = (const unsigned short*)&b4;
#pragma unroll
            for (int j = 0; j < 8; j++)
                s[p * 135 + g * 8 + j] = b2f(au[j]) + b2f(bu[j]);
        }
        __syncthreads();
        // phase2: write NCHW coalesced + pooled wave-reduction
        int p = t & 63, cw = t >> 6;
#pragma unroll
        for (int i = 0; i < 32; i++) {
            int c = cw * 32 + i;
            float v = s[p * 135 + c];
            p2d[(size_t)(cb + c) * NPIX + p0 + p] = v;
            float sum = v;
#pragma unroll
            for (int off = 32; off > 0; off >>= 1) sum += __shfl_down(sum, off, 64);
            if (p == 0) atomicAdd(acc + n * CDIM + cb + c, sum);
        }
        __syncthreads();
    }
}

__global__ __launch_bounds__(256) void pooled_scale_kernel(
    const float* __restrict__ acc, float* __restrict__ dout)
{
    int i = blockIdx.x * 256 + threadIdx.x;
    if (i < 6144) dout[i] = acc[i] * (1.f / 3136.f);
}

extern "C" void kernel_launch(void* const* d_in, const int* in_sizes, int n_in,
                              void* d_out, int out_size, void* d_ws, size_t ws_size,
                              hipStream_t stream)
{
    const float* i_features = (const float*)d_in[1];
    const float* p_motions  = (const float*)d_in[2];
    const float* dw  = (const float*)d_in[3];
    const float* db  = (const float*)d_in[4];
    const float* mw1 = (const float*)d_in[5];
    const float* mb1 = (const float*)d_in[6];
    const float* mw2 = (const float*)d_in[7];
    const float* mb2 = (const float*)d_in[8];
    const float* mw3 = (const float*)d_in[9];
    const float* mb3 = (const float*)d_in[10];
    const float* ew1 = (const float*)d_in[11];
    const float* eb1 = (const float*)d_in[12];
    const float* ew2 = (const float*)d_in[13];
    const float* eb2 = (const float*)d_in[14];
    const float* ew3 = (const float*)d_in[15];
    const float* eb3 = (const float*)d_in[16];
    const float* ew4 = (const float*)d_in[17];
    const float* eb4 = (const float*)d_in[18];
    float* out = (float*)d_out;

    // workspace layout (bytes)
    char* p = (char*)d_ws;
    float* pm = (float*)p;            p += 602112;
    float* acc = (float*)p;           p += 24576;
    unsigned short* wpE2 = (unsigned short*)p; p += 1179648;
    unsigned short* wpE3 = (unsigned short*)p; p += 1179648;
    unsigned short* wpE4 = (unsigned short*)p; p += 1179648;
    unsigned short* wpM1 = (unsigned short*)p; p += 1179648;
    unsigned short* wpM2 = (unsigned short*)p; p += 1179648;
    unsigned short* wpM3 = (unsigned short*)p; p += 1179648;
    unsigned short* wpDW = (unsigned short*)p; p += 131072;
    unsigned short* actA = (unsigned short*)p; p += 38535168;
    unsigned short* actB = (unsigned short*)p; p += 38535168;
    unsigned short* embB = (unsigned short*)p; p += 38535168;

    hipMemsetAsync(acc, 0, 6144 * sizeof(float), stream);

    resize_pm_kernel<<<(NN * 2 * NPIX + 255) / 256, 256, 0, stream>>>(p_motions, pm);

    int pk3 = (8 * 256 * 288 + 255) / 256;
    pack3_kernel<<<pk3, 256, 0, stream>>>(ew2, wpE2);
    pack3_kernel<<<pk3, 256, 0, stream>>>(ew3, wpE3);
    pack3_kernel<<<pk3, 256, 0, stream>>>(ew4, wpE4);
    pack3_kernel<<<pk3, 256, 0, stream>>>(mw1, wpM1);
    pack3_kernel<<<pk3, 256, 0, stream>>>(mw2, wpM2);
    pack3_kernel<<<pk3, 256, 0, stream>>>(mw3, wpM3);
    pack1_kernel<<<(8 * 256 * 32 + 255) / 256, 256, 0, stream>>>(dw, wpDW);

    // emb chain (bf16 NHWC)
    ew1_kernel<<<dim3(392, NN), 256, 0, stream>>>(pm, ew1, eb1, actA);
    dim3 cg24(16, 4, NN), cg8(16, 4, 8);
    conv_mfma<9, true, true><<<cg24, 256, 0, stream>>>(actA, wpE2, eb2, actB);
    conv_mfma<9, true, true><<<cg24, 256, 0, stream>>>(actB, wpE3, eb3, actA);
    conv_mfma<9, true, true><<<cg24, 256, 0, stream>>>(actA, wpE4, eb4, embB);

    // Z = dw * i_features (on the 8 unique maps), then deform-sample Z (+db)
    transpose_fI<<<dim3(49, 4, 8), 256, 0, stream>>>(i_features, actA);
    conv_mfma<1, false, false><<<cg8, 256, 0, stream>>>(actA, wpDW, nullptr, actB);
    deform_kernel<<<dim3(392, NN), 256, 0, stream>>>(actB, pm, db, actA);

    // pf chain
    conv_mfma<9, true, true><<<cg24, 256, 0, stream>>>(actA, wpM1, mb1, actB);
    conv_mfma<9, true, true><<<cg24, 256, 0, stream>>>(actB, wpM2, mb2, actA);
    conv_mfma<9, true, true><<<cg24, 256, 0, stream>>>(actA, wpM3, mb3, actB);

    // p2d + pooled
    final_kernel<<<dim3(49, NN), 256, 0, stream>>>(actB, embB, out, acc);
    pooled_scale_kernel<<<24, 256, 0, stream>>>(acc, out);
}